// Round 2
// baseline (1184.892 us; speedup 1.0000x reference)
//
#include <hip/hip_runtime.h>

// FusedLoRA, single fused kernel.
// x[4,4096,4096] f32; 3x (A[4096,8] randn, B[8,4096] zeros) f32
// out[16384][12288] = concat_l( (x @ A_l) @ B_l ), scale = 1.0
//
// Per block (256 thr, 4 waves): own 16 rows.
//   Phase A: xa[16][24] = x_rows @ [A0|A1|A2]  (k-chunked, A staged transposed in LDS)
//   Phase B: out[16][12288] = xa @ blockdiag(B0,B1,B2)  (B frags from L2, coalesced stores)
// HBM: 256 MiB x read + 768 MiB out write ≈ 163 us floor at 6.3 TB/s.

#define DIM       4096
#define M_ROWS    16384
#define RANK      8
#define NC        24             // 3 loras * rank 8
#define OUT_COLS  12288

#define KC             256       // K-chunk; At = 24*256*4 = 24 KB LDS
#define ROWS_PER_WAVE  4
#define ROWS_PER_BLOCK 16        // 4 waves * 4 rows

__launch_bounds__(256, 2)
__global__ void lora_fused_kernel(const float* __restrict__ x,
                                  const float* __restrict__ A0,
                                  const float* __restrict__ A1,
                                  const float* __restrict__ A2,
                                  const float* __restrict__ B0,
                                  const float* __restrict__ B1,
                                  const float* __restrict__ B2,
                                  float* __restrict__ out) {
  // At transposed: compute-read At[c][4*lane] is contiguous across lanes -> conflict-free b128.
  __shared__ float At[NC][KC];                   // 24 KB
  __shared__ float xa_s[ROWS_PER_BLOCK][NC];     // 1.5 KB

  const int tid   = threadIdx.x;
  const int lane  = tid & 63;
  const int wave  = tid >> 6;
  const int row0b = blockIdx.x * ROWS_PER_BLOCK;
  const int row0  = row0b + wave * ROWS_PER_WAVE;

  // ---------------- Phase A: xa = x @ [A0|A1|A2] ----------------
  float acc[ROWS_PER_WAVE][NC];
#pragma unroll
  for (int r = 0; r < ROWS_PER_WAVE; ++r)
#pragma unroll
    for (int c = 0; c < NC; ++c) acc[r][c] = 0.f;

  for (int kb = 0; kb < DIM; kb += KC) {
    // Stage A chunk transposed. Per lora: KC*8 floats = 512 float4; 3 loras = 1536 float4
    // over 256 threads -> 6 float4/thread. Write bank pattern: 2 lanes/bank (free).
#pragma unroll
    for (int j = 0; j < 6; ++j) {
      const int l   = j >> 1;                    // compile-time after unroll
      const int idx = tid + (j & 1) * 256;       // float4 index within lora chunk
      const int dof = idx >> 1;                  // k offset in chunk
      const int rq  = (idx & 1) * 4;             // rank quad: 0 or 4
      const float* Ap = (l == 0) ? A0 : (l == 1) ? A1 : A2;
      const float4 v = *(const float4*)(Ap + (size_t)(kb + dof) * RANK + rq);
      At[l * RANK + rq + 0][dof] = v.x;
      At[l * RANK + rq + 1][dof] = v.y;
      At[l * RANK + rq + 2][dof] = v.z;
      At[l * RANK + rq + 3][dof] = v.w;
    }
    __syncthreads();

    // One compute step: 64 lanes * 4 floats = 256 = KC.
    const int kl = 4 * lane;
    float4 xv[ROWS_PER_WAVE];
#pragma unroll
    for (int r = 0; r < ROWS_PER_WAVE; ++r)
      xv[r] = *(const float4*)(x + (size_t)(row0 + r) * DIM + kb + kl);
#pragma unroll
    for (int c = 0; c < NC; ++c) {
      const float4 av = *(const float4*)(&At[c][kl]);
#pragma unroll
      for (int r = 0; r < ROWS_PER_WAVE; ++r) {
        acc[r][c] = fmaf(xv[r].x, av.x, acc[r][c]);
        acc[r][c] = fmaf(xv[r].y, av.y, acc[r][c]);
        acc[r][c] = fmaf(xv[r].z, av.z, acc[r][c]);
        acc[r][c] = fmaf(xv[r].w, av.w, acc[r][c]);
      }
    }
    __syncthreads();
  }

  // 64-lane butterfly reduction per (row, col)
#pragma unroll
  for (int r = 0; r < ROWS_PER_WAVE; ++r)
#pragma unroll
    for (int c = 0; c < NC; ++c) {
      float v = acc[r][c];
#pragma unroll
      for (int off = 32; off > 0; off >>= 1) v += __shfl_xor(v, off, 64);
      acc[r][c] = v;
    }

  // lane c owns column c; park xa in LDS
  float outv[ROWS_PER_WAVE];
#pragma unroll
  for (int c = 0; c < NC; ++c)
#pragma unroll
    for (int r = 0; r < ROWS_PER_WAVE; ++r)
      if (lane == c) outv[r] = acc[r][c];

  if (lane < NC) {
#pragma unroll
    for (int r = 0; r < ROWS_PER_WAVE; ++r)
      xa_s[wave * ROWS_PER_WAVE + r][lane] = outv[r];
  }
  __syncthreads();

  // ---------------- Phase B: out = xa @ blockdiag(B) ----------------
  // 12 col-tiles of 1024 (256 thr * float4); tiles 0-3 -> lora 0, etc.
#pragma unroll
  for (int ct = 0; ct < 12; ++ct) {
    const int l  = ct >> 2;                       // compile-time after unroll
    const int oc = ct * 1024 + tid * 4;           // global out col
    const int ob = oc - l * DIM;                  // col within B_l
    const float* B = (l == 0) ? B0 : (l == 1) ? B1 : B2;

    float4 b[RANK];                               // 32 VGPRs, L2-resident loads
#pragma unroll
    for (int r = 0; r < RANK; ++r)
      b[r] = *(const float4*)(B + (size_t)r * DIM + ob);

#pragma unroll 4
    for (int i = 0; i < ROWS_PER_BLOCK; ++i) {
      // broadcast LDS reads (all lanes same addr)
      const float4 s0 = *(const float4*)(&xa_s[i][l * RANK]);
      const float4 s1 = *(const float4*)(&xa_s[i][l * RANK + 4]);
      const float s[8] = {s0.x, s0.y, s0.z, s0.w, s1.x, s1.y, s1.z, s1.w};

      float4 av = {0.f, 0.f, 0.f, 0.f};
#pragma unroll
      for (int r = 0; r < RANK; ++r) {
        av.x = fmaf(s[r], b[r].x, av.x);
        av.y = fmaf(s[r], b[r].y, av.y);
        av.z = fmaf(s[r], b[r].z, av.z);
        av.w = fmaf(s[r], b[r].w, av.w);
      }
      *(float4*)(out + (size_t)(row0b + i) * OUT_COLS + oc) = av;
    }
  }
}

extern "C" void kernel_launch(void* const* d_in, const int* in_sizes, int n_in,
                              void* d_out, int out_size, void* d_ws, size_t ws_size,
                              hipStream_t stream) {
  const float* x  = (const float*)d_in[0];
  const float* A0 = (const float*)d_in[1];
  const float* B0 = (const float*)d_in[2];
  const float* A1 = (const float*)d_in[3];
  const float* B1 = (const float*)d_in[4];
  const float* A2 = (const float*)d_in[5];
  const float* B2 = (const float*)d_in[6];
  float* out = (float*)d_out;

  lora_fused_kernel<<<dim3(M_ROWS / ROWS_PER_BLOCK), dim3(256), 0, stream>>>(
      x, A0, A1, A2, B0, B1, B2, out);
}